// Round 5
// baseline (15769.400 us; speedup 1.0000x reference)
//
#include <hip/hip_runtime.h>
#include <math.h>

#define Bn 128
#define Pn 625
#define ENCn 512
#define An 256
#define En 256
#define Hn 512
#define Vn 70
#define G4n 2048
#define STARTT 68
#define ENDT 69
#define NCHUNK 5
#define PCH 125
#define SSTRIDE 640
#define PAWS (Bn * 512)
#define KSPLIT 16
#define KCH 80

__device__ __forceinline__ float sigm(float x) { return 1.f / (1.f + expf(-x)); }

// identical pointwise LSTM math in both contexts (same inlined IR -> same contraction)
__device__ __forceinline__ float lstm_h(const float* __restrict__ gp, int b, int u,
                                        const float* __restrict__ bih,
                                        const float* __restrict__ bhh,
                                        float c_in, float* cv_out) {
  float gi = bih[u] + bhh[u];
  float gf = bih[u + 512] + bhh[u + 512];
  float gg = bih[u + 1024] + bhh[u + 1024];
  float go = bih[u + 1536] + bhh[u + 1536];
  for (int s = 0; s < KSPLIT; ++s) {
    const float* row = gp + ((size_t)s * Bn + b) * G4n;
    gi += row[u];
    gf += row[u + 512];
    gg += row[u + 1024];
    go += row[u + 1536];
  }
  float cv = sigm(gf) * c_in + sigm(gi) * tanhf(gg);
  *cv_out = cv;
  return sigm(go) * tanhf(cv);
}

// ---------------- setup kernels ----------------

__global__ __launch_bounds__(256) void k_mean(const float* __restrict__ enc,
                                              float* __restrict__ mean_enc) {
  int b = blockIdx.x, t = threadIdx.x;
  const float* e = enc + (size_t)b * Pn * ENCn;
  float s0 = 0.f, s1 = 0.f;
  for (int p = 0; p < Pn; ++p) {
    s0 += e[(size_t)p * ENCn + t];
    s1 += e[(size_t)p * ENCn + t + 256];
  }
  mean_enc[b * ENCn + t] = s0 * (1.0f / 625.0f);
  mean_enc[b * ENCn + t + 256] = s1 * (1.0f / 625.0f);
}

__global__ __launch_bounds__(512) void k_init(const float* __restrict__ mean_enc,
                       const float* __restrict__ Wh0, const float* __restrict__ bh0,
                       const float* __restrict__ Wc0, const float* __restrict__ bc0,
                       const float* __restrict__ emb,
                       float* __restrict__ h0, float* __restrict__ c0,
                       float* __restrict__ emb_t, int* __restrict__ done_arr) {
  int b = blockIdx.x, t = threadIdx.x;
  const float* W = blockIdx.y ? Wc0 : Wh0;
  const float* bias = blockIdx.y ? bc0 : bh0;
  float* out = blockIdx.y ? c0 : h0;
  __shared__ float ms[ENCn];
  ms[t] = mean_enc[b * ENCn + t];
  __syncthreads();
  float s = bias[t];
  for (int k = 0; k < ENCn; ++k) s += ms[k] * W[k * Hn + t];
  out[b * Hn + t] = s;
  if (blockIdx.y == 0 && t < En) emb_t[b * En + t] = emb[STARTT * En + t];
  if (blockIdx.y == 0 && b == 0 && t == 0) done_arr[0] = 0;
}

// att1 = enc @ We + be : [80000,512] @ [512,256], fp32 tiled 128x128
__global__ __launch_bounds__(256) void k_att1(const float* __restrict__ Am,
                       const float* __restrict__ We,
                       const float* __restrict__ be, float* __restrict__ att1) {
  __shared__ float sA[16][128];
  __shared__ float sB[16][128];
  int n0 = blockIdx.x * 128, m0 = blockIdx.y * 128;
  int t = threadIdx.x;
  int tm = (t >> 4) * 8, tn = (t & 15) * 8;
  float acc[8][8];
#pragma unroll
  for (int i = 0; i < 8; ++i)
#pragma unroll
    for (int j = 0; j < 8; ++j) acc[i][j] = 0.f;
  for (int k0 = 0; k0 < 512; k0 += 16) {
    __syncthreads();
#pragma unroll
    for (int i = 0; i < 8; ++i) {
      int idx = t + i * 256;
      int mm = idx >> 4, kk = idx & 15;
      sA[kk][mm] = Am[(size_t)(m0 + mm) * 512 + k0 + kk];
      int kk2 = idx >> 7, nn = idx & 127;
      sB[kk2][nn] = We[(size_t)(k0 + kk2) * 256 + n0 + nn];
    }
    __syncthreads();
#pragma unroll
    for (int kk = 0; kk < 16; ++kk) {
      float a[8], bq[8];
      *(float4*)&a[0] = *(const float4*)&sA[kk][tm];
      *(float4*)&a[4] = *(const float4*)&sA[kk][tm + 4];
      *(float4*)&bq[0] = *(const float4*)&sB[kk][tn];
      *(float4*)&bq[4] = *(const float4*)&sB[kk][tn + 4];
#pragma unroll
      for (int i = 0; i < 8; ++i)
#pragma unroll
        for (int j = 0; j < 8; ++j) acc[i][j] += a[i] * bq[j];
    }
  }
  float ber[8];
  *(float4*)&ber[0] = *(const float4*)&be[n0 + tn];
  *(float4*)&ber[4] = *(const float4*)&be[n0 + tn + 4];
#pragma unroll
  for (int i = 0; i < 8; ++i) {
    float o[8];
#pragma unroll
    for (int j = 0; j < 8; ++j) o[j] = acc[i][j] + ber[j];
    *(float4*)&att1[(size_t)(m0 + tm + i) * An + n0 + tn] = *(float4*)&o[0];
    *(float4*)&att1[(size_t)(m0 + tm + i) * An + n0 + tn + 4] = *(float4*)&o[4];
  }
}

// one-time proj from h0 (step-0 att2/gate)
__global__ __launch_bounds__(256) void k_proj0(const float* __restrict__ h,
                       const float* __restrict__ Wd, const float* __restrict__ bd,
                       const float* __restrict__ Wb, const float* __restrict__ bbv,
                       float* __restrict__ att2, float* __restrict__ gate) {
  int b = blockIdx.x, t = threadIdx.x;
  __shared__ float hsh[Hn];
  hsh[t] = h[b * Hn + t];
  hsh[t + 256] = h[b * Hn + t + 256];
  __syncthreads();
  float s0 = bd[t];
  float s1 = bbv[t], s2 = bbv[t + 256];
  for (int k = 0; k < Hn; ++k) {
    float hv = hsh[k];
    s0 += hv * Wd[(size_t)k * An + t];
    s1 += hv * Wb[(size_t)k * ENCn + t];
    s2 += hv * Wb[(size_t)k * ENCn + t + 256];
  }
  att2[b * An + t] = s0;
  gate[b * ENCn + t] = sigm(s1);
  gate[b * ENCn + t + 256] = sigm(s2);
}

// ---------------- per-step kernels (4 launches/step) ----------------

// scores: e -> chunk softmax stats; writes exp(e - m_c) + (m_c, l_c).
// block 640: flat argmax over prev row maxima -> done.
__global__ __launch_bounds__(256) void k_score(const float* __restrict__ att1,
                       const float* __restrict__ att2,
                       const float* __restrict__ wf, const float* __restrict__ bfp,
                       float* __restrict__ scores, float* __restrict__ stats,
                       const float* __restrict__ rowval, const int* __restrict__ rowidx,
                       int* __restrict__ done_f, int do_flat) {
  int t = threadIdx.x;
  if (blockIdx.x == 640) {
    if (!do_flat) return;
    __shared__ float sv[128];
    __shared__ int si[128];
    if (t < 128) { sv[t] = rowval[t]; si[t] = t * Vn + rowidx[t]; }
    __syncthreads();
    for (int s = 64; s > 0; s >>= 1) {
      if (t < s) {
        if (sv[t + s] > sv[t] || (sv[t + s] == sv[t] && si[t + s] < si[t])) {
          sv[t] = sv[t + s]; si[t] = si[t + s];
        }
      }
      __syncthreads();
    }
    if (t == 0 && si[0] == ENDT) *done_f = 1;
    return;
  }
  int c = blockIdx.x % NCHUNK, b = blockIdx.x / NCHUNK;
  int lane = t & 63, wv = t >> 6;
  int p0 = c * PCH;
  __shared__ float es[PCH];
  __shared__ float red[256];
  float4 a2 = ((const float4*)(att2 + b * An))[lane];
  float4 wfr = ((const float4*)wf)[lane];
  float bfv = *bfp;
  const float* a1b = att1 + ((size_t)b * Pn + p0) * An;
  for (int p = wv; p < PCH; p += 4) {
    float4 v = ((const float4*)(a1b + (size_t)p * An))[lane];
    float s = fmaxf(v.x + a2.x, 0.f) * wfr.x
            + fmaxf(v.y + a2.y, 0.f) * wfr.y
            + fmaxf(v.z + a2.z, 0.f) * wfr.z
            + fmaxf(v.w + a2.w, 0.f) * wfr.w;
    for (int o = 32; o > 0; o >>= 1) s += __shfl_down(s, o, 64);
    if (lane == 0) es[p] = s + bfv;
  }
  __syncthreads();
  float m = -1e30f;
  for (int i = t; i < PCH; i += 256) m = fmaxf(m, es[i]);
  red[t] = m;
  __syncthreads();
  for (int s = 128; s > 0; s >>= 1) {
    if (t < s) red[t] = fmaxf(red[t], red[t + s]);
    __syncthreads();
  }
  m = red[0];
  __syncthreads();
  float lp = 0.f;
  for (int i = t; i < PCH; i += 256) {
    float e2 = expf(es[i] - m);
    es[i] = e2;
    lp += e2;
  }
  red[t] = lp;
  __syncthreads();
  for (int s = 128; s > 0; s >>= 1) {
    if (t < s) red[t] += red[t + s];
    __syncthreads();
  }
  if (t < PCH) scores[b * SSTRIDE + p0 + t] = es[t];
  if (t == 0) {
    stats[(b * NCHUNK + c) * 2] = m;
    stats[(b * NCHUNK + c) * 2 + 1] = red[0];
  }
}

// value: gated, fully-scaled partial awe per chunk. grid 640 x 256.
__global__ __launch_bounds__(256) void k_value(const float* __restrict__ scores,
                       const float* __restrict__ stats,
                       const float* __restrict__ gate,
                       const float* __restrict__ enc, float* __restrict__ paw) {
  int c = blockIdx.x % NCHUNK, b = blockIdx.x / NCHUNK, t = threadIdx.x;
  int p0 = c * PCH;
  float mv[NCHUNK], lv[NCHUNK];
  float M = -1e30f;
#pragma unroll
  for (int cc = 0; cc < NCHUNK; ++cc) {
    mv[cc] = stats[(b * NCHUNK + cc) * 2];
    lv[cc] = stats[(b * NCHUNK + cc) * 2 + 1];
    M = fmaxf(M, mv[cc]);
  }
  float L = 0.f;
#pragma unroll
  for (int cc = 0; cc < NCHUNK; ++cc) L += expf(mv[cc] - M) * lv[cc];
  float scinv = expf(mv[c] - M) * (1.f / L);
  float2 g = ((const float2*)(gate + b * ENCn))[t];
  const float* sp = scores + b * SSTRIDE + p0;
  const float2* eb2 = (const float2*)(enc + ((size_t)b * Pn + p0) * ENCn);
  float a0 = 0.f, a1 = 0.f;
#pragma unroll 5
  for (int p = 0; p < PCH; ++p) {
    float wp = sp[p] * scinv;
    float2 v = eb2[(size_t)p * 256 + t];
    a0 += wp * v.x;
    a1 += wp * v.y;
  }
  ((float2*)(paw + (size_t)(c * Bn + b) * 512))[t] = make_float2(a0 * g.x, a1 * g.y);
}

// gates split-K GEMM; awe columns read as 5-way partial sum.
__global__ __launch_bounds__(256) void k_gates(const float* __restrict__ embt,
                       const float* __restrict__ paw, const float* __restrict__ h,
                       const float* __restrict__ Wih, const float* __restrict__ Whh,
                       float* __restrict__ gp) {
  int n0 = blockIdx.x * 64;
  int sI = blockIdx.y;
  int k0 = sI * KCH;
  int t = threadIdx.x;
  int tc = t & 15, tg = t >> 4;
  int nc = n0 + tc * 4;
  float4 acc[8];
#pragma unroll
  for (int r = 0; r < 8; ++r) acc[r] = make_float4(0.f, 0.f, 0.f, 0.f);
  for (int kk = 0; kk < KCH; kk += 4) {
    int k = k0 + kk;
    const float* wbase = (k < 768) ? (Wih + (size_t)k * G4n + nc)
                                   : (Whh + (size_t)(k - 768) * G4n + nc);
    float4 w0 = *(const float4*)(wbase);
    float4 w1 = *(const float4*)(wbase + G4n);
    float4 w2 = *(const float4*)(wbase + 2 * G4n);
    float4 w3 = *(const float4*)(wbase + 3 * G4n);
#pragma unroll
    for (int r = 0; r < 8; ++r) {
      int row = tg * 8 + r;
      float4 xv;
      if (k < 256) {
        xv = *(const float4*)(embt + row * En + k);
      } else if (k < 768) {
        const float* pb = paw + (size_t)row * 512 + (k - 256);
        float4 x0 = *(const float4*)(pb);
        float4 x1 = *(const float4*)(pb + PAWS);
        float4 x2 = *(const float4*)(pb + 2 * PAWS);
        float4 x3 = *(const float4*)(pb + 3 * PAWS);
        float4 x4 = *(const float4*)(pb + 4 * PAWS);
        xv.x = (((x0.x + x1.x) + x2.x) + x3.x) + x4.x;
        xv.y = (((x0.y + x1.y) + x2.y) + x3.y) + x4.y;
        xv.z = (((x0.z + x1.z) + x2.z) + x3.z) + x4.z;
        xv.w = (((x0.w + x1.w) + x2.w) + x3.w) + x4.w;
      } else {
        xv = *(const float4*)(h + row * Hn + (k - 768));
      }
      acc[r].x += xv.x * w0.x + xv.y * w1.x + xv.z * w2.x + xv.w * w3.x;
      acc[r].y += xv.x * w0.y + xv.y * w1.y + xv.z * w2.y + xv.w * w3.y;
      acc[r].z += xv.x * w0.z + xv.y * w1.z + xv.z * w2.z + xv.w * w3.z;
      acc[r].w += xv.x * w0.w + xv.y * w1.w + xv.z * w2.w + xv.w * w3.w;
    }
  }
#pragma unroll
  for (int r = 0; r < 8; ++r)
    *(float4*)(gp + ((size_t)sI * Bn + tg * 8 + r) * G4n + nc) = acc[r];
}

// blocks 0..127: lstm reduce + pointwise + preds GEMV + out + argmax + emb.
// blocks 128..191: recompute h (identical math) for 2 rows, compute next att2/gate.
__global__ __launch_bounds__(512) void k_lstm(const float* __restrict__ gp,
                       const float* __restrict__ bih, const float* __restrict__ bhh,
                       const float* __restrict__ c_in, float* __restrict__ c_out,
                       float* __restrict__ h_out,
                       const float* __restrict__ Wfc, const float* __restrict__ bfc,
                       const float* __restrict__ emb,
                       float* __restrict__ rowval, int* __restrict__ rowidx,
                       float* __restrict__ emb_next, float* __restrict__ out,
                       const int* __restrict__ done_t, int step, int T,
                       const float* __restrict__ Wd, const float* __restrict__ bd,
                       const float* __restrict__ Wb, const float* __restrict__ bbv,
                       float* __restrict__ att2, float* __restrict__ gate,
                       int do_proj) {
  int blk = blockIdx.x, t = threadIdx.x;
  __shared__ float hs[1024];
  __shared__ float ps[Vn];
  __shared__ int tokS;
  if (blk < Bn) {
    int b = blk;
    float cv;
    float hv = lstm_h(gp, b, t, bih, bhh, c_in[b * Hn + t], &cv);
    c_out[b * Hn + t] = cv;
    h_out[b * Hn + t] = hv;
    hs[t] = hv;
    __syncthreads();
    int lane = t & 63, wvi = t >> 6;
    for (int v = wvi; v < Vn; v += 8) {
      float s = 0.f;
      for (int k = lane; k < Hn; k += 64) s += hs[k] * Wfc[(size_t)k * Vn + v];
      for (int o = 32; o > 0; o >>= 1) s += __shfl_down(s, o, 64);
      if (lane == 0) ps[v] = s + bfc[v];
    }
    __syncthreads();
    int done = *done_t;
    if (t < Vn) out[((size_t)b * T + step) * Vn + t] = done ? 0.f : ps[t];
    if (t == 0) {
      float bv = ps[0]; int bi = 0;
      for (int v = 1; v < Vn; ++v)
        if (ps[v] > bv) { bv = ps[v]; bi = v; }
      rowval[b] = bv; rowidx[b] = bi; tokS = bi;
    }
    __syncthreads();
    if (t < En) emb_next[b * En + t] = emb[tokS * En + t];
  } else {
    if (!do_proj) return;
    int r0 = (blk - Bn) * 2;
#pragma unroll
    for (int rr = 0; rr < 2; ++rr) {
      int b = r0 + rr;
      float cv;
      hs[rr * 512 + t] = lstm_h(gp, b, t, bih, bhh, c_in[b * Hn + t], &cv);
    }
    __syncthreads();
#pragma unroll
    for (int i = 0; i < 3; ++i) {
      int idx = i * 512 + t;       // 0..1535 = 2 rows x 768 cols
      int row = idx / 768, col = idx % 768;
      int b = r0 + row;
      const float* hrow = hs + row * 512;
      if (col < 256) {
        float s = bd[col];
#pragma unroll 4
        for (int k = 0; k < Hn; ++k) s += hrow[k] * Wd[(size_t)k * An + col];
        att2[b * An + col] = s;
      } else {
        int cc = col - 256;
        float s = bbv[cc];
#pragma unroll 4
        for (int k = 0; k < Hn; ++k) s += hrow[k] * Wb[(size_t)k * ENCn + cc];
        gate[b * ENCn + cc] = sigm(s);
      }
    }
  }
}

// ---------------- host ----------------

extern "C" void kernel_launch(void* const* d_in, const int* in_sizes, int n_in,
                              void* d_out, int out_size, void* d_ws, size_t ws_size,
                              hipStream_t stream) {
  const float* enc = (const float*)d_in[0];
  const float* emb = (const float*)d_in[1];
  const float* We  = (const float*)d_in[2];
  const float* be  = (const float*)d_in[3];
  const float* Wd  = (const float*)d_in[4];
  const float* bd  = (const float*)d_in[5];
  const float* wf  = (const float*)d_in[6];
  const float* bf  = (const float*)d_in[7];
  const float* Wh0 = (const float*)d_in[8];
  const float* bh0 = (const float*)d_in[9];
  const float* Wc0 = (const float*)d_in[10];
  const float* bc0 = (const float*)d_in[11];
  const float* Wb  = (const float*)d_in[12];
  const float* bb  = (const float*)d_in[13];
  const float* Wih = (const float*)d_in[14];
  const float* Whh = (const float*)d_in[15];
  const float* bih = (const float*)d_in[16];
  const float* bhh = (const float*)d_in[17];
  const float* Wfc = (const float*)d_in[18];
  const float* bfc = (const float*)d_in[19];
  int T = out_size / (Bn * Vn);  // 70

  float* w = (float*)d_ws;
  size_t off = 0;
  float* att1 = w + off;     off += (size_t)Bn * Pn * An;
  float* mean_enc = w + off; off += Bn * ENCn;
  float* hb0 = w + off;      off += Bn * Hn;
  float* hb1 = w + off;      off += Bn * Hn;
  float* cb0 = w + off;      off += Bn * Hn;
  float* cb1 = w + off;      off += Bn * Hn;
  float* eb0 = w + off;      off += Bn * En;
  float* eb1 = w + off;      off += Bn * En;
  float* att2 = w + off;     off += Bn * An;
  float* gate = w + off;     off += Bn * ENCn;
  float* scores = w + off;   off += (size_t)Bn * SSTRIDE;
  float* stats = w + off;    off += Bn * NCHUNK * 2;
  float* paw = w + off;      off += (size_t)NCHUNK * Bn * 512;
  float* gatesP = w + off;   off += (size_t)KSPLIT * Bn * G4n;
  float* rowval = w + off;   off += 256;
  off = (off + 255) & ~(size_t)255;
  int* rowidx = (int*)(w + off); off += 256;
  int* done_arr = (int*)(w + off);

  float* hbuf[2] = {hb0, hb1};
  float* cbuf[2] = {cb0, cb1};
  float* ebuf[2] = {eb0, eb1};

  k_mean<<<Bn, 256, 0, stream>>>(enc, mean_enc);
  k_init<<<dim3(Bn, 2), 512, 0, stream>>>(mean_enc, Wh0, bh0, Wc0, bc0, emb,
                                          hb0, cb0, eb0, done_arr);
  k_att1<<<dim3(2, 625), 256, 0, stream>>>(enc, We, be, att1);
  k_proj0<<<Bn, 256, 0, stream>>>(hb0, Wd, bd, Wb, bb, att2, gate);

  int cur = 0;
  for (int t = 0; t < T; ++t) {
    int nxt = cur ^ 1;
    k_score<<<641, 256, 0, stream>>>(att1, att2, wf, bf, scores, stats,
                                     rowval, rowidx, done_arr, t > 0 ? 1 : 0);
    k_value<<<640, 256, 0, stream>>>(scores, stats, gate, enc, paw);
    k_gates<<<dim3(32, KSPLIT), 256, 0, stream>>>(ebuf[cur], paw, hbuf[cur], Wih, Whh, gatesP);
    k_lstm<<<192, 512, 0, stream>>>(gatesP, bih, bhh, cbuf[cur], cbuf[nxt], hbuf[nxt],
                                    Wfc, bfc, emb, rowval, rowidx, ebuf[nxt], (float*)d_out,
                                    done_arr, t, T,
                                    Wd, bd, Wb, bb, att2, gate, t < T - 1 ? 1 : 0);
    cur = nxt;
  }
}